// Round 3
// baseline (249.342 us; speedup 1.0000x reference)
//
#include <hip/hip_runtime.h>
#include <hip/hip_bf16.h>
#include <math.h>

// GPT-OSS MoE: rmsnorm -> gate top4 -> mxfp4 MLP1 (MFMA) -> swiglu -> mxfp4 MLP2 (MFMA) -> combine
// E=32, H=1024, I=1024, N=1024 tokens, top-4.

#define NE 32
#define HD 1024
#define ID 1024
#define NTOK 1024
#define R1 2048
#define TCH 192          // token chunk: 6 m-tiles of 32

typedef __attribute__((ext_vector_type(8)))  short bf16x8;
typedef __attribute__((ext_vector_type(16))) float f32x16;

// ---- workspace layout (bytes) ----
#define TB_OFF   0            // t_bf16 [1024][1024] bf16 = 2 MB
#define A_OFF    2097152      // a      [4096][1024] bf16 = 8 MB
#define YB_OFF   10485760     // yb     [4096][1024] bf16 = 8 MB
#define CNT_OFF  18874368     // counts int[32]
#define OFFS_OFF 18874624     // offsets int[33]
#define TOKL_OFF 18874880     // tok_list int[32*1024]
#define TIDX_OFF 19005952     // top_idx int[1024*4]
#define TWT_OFF  19022336     // top_wt  f32[1024*4]
#define POS_OFF  19038720     // pos_of  int[1024*4]

__device__ __forceinline__ unsigned f2bf(float f) {
    unsigned u = __float_as_uint(f);
    return (u + 0x7FFFu + ((u >> 16) & 1u)) >> 16;   // RNE
}
__device__ __forceinline__ float bf2f(unsigned u) {
    return __uint_as_float(u << 16);
}

// decode 8 fp4 elems (4 boxed int32s = 4 bytes = 8 nibbles) -> bf16x8, scale folded
// as packed exponent add. fp4 "zero" encoded as 2^-87 -> ~2^-96 after scale (negligible).
__device__ __forceinline__ bf16x8 dec8(int4 wv, unsigned dd) {
    unsigned u = __builtin_amdgcn_perm((unsigned)wv.y, (unsigned)wv.x, 0x00000400u);
    unsigned v = __builtin_amdgcn_perm((unsigned)wv.w, (unsigned)wv.z, 0x04000000u);
    unsigned packed = __builtin_amdgcn_perm(v, u, 0x07060100u);   // {b0,b1,b2,b3}
    unsigned selE = packed & 0x07070707u;
    unsigned sE   = packed & 0x08080808u;
    unsigned ph   = packed >> 4;
    unsigned selO = ph & 0x07070707u;
    unsigned sO   = ph & 0x08080808u;
    const unsigned PH_hi = 0x40404040u, PH_lo = 0x3F3F3F14u;
    const unsigned PL_hi = 0xC0804000u, PL_lo = 0xC0800000u;
    unsigned hbE = __builtin_amdgcn_perm(PH_hi, PH_lo, selE) | (sE << 4);
    unsigned lbE = __builtin_amdgcn_perm(PL_hi, PL_lo, selE);
    unsigned hbO = __builtin_amdgcn_perm(PH_hi, PH_lo, selO) | (sO << 4);
    unsigned lbO = __builtin_amdgcn_perm(PL_hi, PL_lo, selO);
    unsigned mE0 = __builtin_amdgcn_perm(hbE, lbE, 0x05010400u);
    unsigned mE1 = __builtin_amdgcn_perm(hbE, lbE, 0x07030602u);
    unsigned mO0 = __builtin_amdgcn_perm(hbO, lbO, 0x05010400u);
    unsigned mO1 = __builtin_amdgcn_perm(hbO, lbO, 0x07030602u);
    unsigned r0 = __builtin_amdgcn_perm(mO0, mE0, 0x05040100u);
    unsigned r1 = __builtin_amdgcn_perm(mO0, mE0, 0x07060302u);
    unsigned r2 = __builtin_amdgcn_perm(mO1, mE1, 0x05040100u);
    unsigned r3 = __builtin_amdgcn_perm(mO1, mE1, 0x07060302u);
    unsigned o0, o1, o2, o3;
    asm("v_pk_add_u16 %0, %1, %2" : "=v"(o0) : "v"(r0), "v"(dd));
    asm("v_pk_add_u16 %0, %1, %2" : "=v"(o1) : "v"(r1), "v"(dd));
    asm("v_pk_add_u16 %0, %1, %2" : "=v"(o2) : "v"(r2), "v"(dd));
    asm("v_pk_add_u16 %0, %1, %2" : "=v"(o3) : "v"(r3), "v"(dd));
    uint4 o; o.x = o0; o.y = o1; o.z = o2; o.w = o3;
    union { uint4 u4; bf16x8 b; } cv; cv.u4 = o;
    return cv.b;
}

__device__ __forceinline__ void block_fence() {
    asm volatile("s_waitcnt lgkmcnt(0)" ::: "memory");
    __builtin_amdgcn_sched_barrier(0);
    __builtin_amdgcn_s_barrier();
    __builtin_amdgcn_sched_barrier(0);
}

__global__ __launch_bounds__(256) void k_gate(
    const float* __restrict__ x, const float* __restrict__ norm_w,
    const float* __restrict__ gate_w, const float* __restrict__ gate_b,
    ushort* __restrict__ t_bf16, int* __restrict__ top_idx, float* __restrict__ top_wt,
    int* __restrict__ counts, int* __restrict__ tok_list, int* __restrict__ pos_of)
{
    int n = blockIdx.x;
    int tid = threadIdx.x;
    __shared__ float tl[HD];
    __shared__ float red[4];
    __shared__ float logits[NE];

    const float4* xv = (const float4*)(x + (size_t)n * HD);
    float4 v = xv[tid];
    float ss = v.x * v.x + v.y * v.y + v.z * v.z + v.w * v.w;
    #pragma unroll
    for (int off = 32; off; off >>= 1) ss += __shfl_down(ss, off);
    if ((tid & 63) == 0) red[tid >> 6] = ss;
    __syncthreads();
    float tot = red[0] + red[1] + red[2] + red[3];
    float rms = rsqrtf(tot * (1.0f / HD) + 1e-5f);

    float4 w = ((const float4*)norm_w)[tid];
    float4 tv;
    tv.x = v.x * rms * w.x; tv.y = v.y * rms * w.y;
    tv.z = v.z * rms * w.z; tv.w = v.w * rms * w.w;
    ushort4 tb;
    tb.x = (ushort)f2bf(tv.x); tb.y = (ushort)f2bf(tv.y);
    tb.z = (ushort)f2bf(tv.z); tb.w = (ushort)f2bf(tv.w);
    ((ushort4*)(t_bf16 + (size_t)n * HD))[tid] = tb;
    ((float4*)tl)[tid] = tv;
    __syncthreads();

    int wv = tid >> 6, lane = tid & 63;
    for (int j = 0; j < 8; j++) {
        int e = wv * 8 + j;
        const float* gw = gate_w + (size_t)e * HD;
        float p = 0.f;
        #pragma unroll
        for (int q = 0; q < 16; q++) { int kk = lane + q * 64; p += tl[kk] * gw[kk]; }
        #pragma unroll
        for (int off = 32; off; off >>= 1) p += __shfl_down(p, off);
        if (lane == 0) logits[e] = p + gate_b[e];
    }
    __syncthreads();

    if (tid == 0) {
        float vals[4]; int idx[4];
        unsigned used = 0;
        #pragma unroll
        for (int kk = 0; kk < 4; kk++) {
            float best = -1e30f; int bi = 0;
            for (int e2 = 0; e2 < NE; e2++) {
                if (used & (1u << e2)) continue;
                if (logits[e2] > best) { best = logits[e2]; bi = e2; }
            }
            used |= 1u << bi; vals[kk] = best; idx[kk] = bi;
        }
        float m = vals[0], s = 0.f, ex[4];
        #pragma unroll
        for (int kk = 0; kk < 4; kk++) { ex[kk] = __expf(vals[kk] - m); s += ex[kk]; }
        float inv = 1.0f / s;
        #pragma unroll
        for (int kk = 0; kk < 4; kk++) {
            top_idx[n * 4 + kk] = idx[kk];
            top_wt[n * 4 + kk] = ex[kk] * inv;
            int slot = atomicAdd(counts + idx[kk], 1);
            tok_list[idx[kk] * NTOK + slot] = n;
            pos_of[n * 4 + kk] = slot;
        }
    }
}

__global__ void k_prefix(const int* __restrict__ counts, int* __restrict__ offsets)
{
    if (threadIdx.x == 0) {
        int s = 0;
        for (int e = 0; e < NE; e++) { offsets[e] = s; s += counts[e]; }
        offsets[NE] = s;
    }
}

// MLP1 (MFMA) + swiglu. Block: expert x 128 rows; 4 waves = 2 row-halves x 2 token-halves.
// Weights: global->reg->dec8->MFMA (no LDS). Tokens: LDS double-buffered, reg-staged.
__global__ __launch_bounds__(256) void k_mlp1(
    const ushort* __restrict__ t_bf16, const int* __restrict__ blocks,
    const int* __restrict__ scales, const float* __restrict__ bias,
    const int* __restrict__ counts, const int* __restrict__ offsets,
    const int* __restrict__ tok_list, ushort* __restrict__ a)
{
    int e = blockIdx.y;
    int cnt = counts[e];
    if (cnt == 0) return;
    int r0 = blockIdx.x * 128;
    int tid = threadIdx.x;
    int w = tid >> 6, l = tid & 63;
    int lr = l & 31, kh = l >> 5;
    int nbase = (w & 1) * 64;
    int tok0 = (w >> 1) * 96;
    int base = offsets[e];

    __shared__ ushort tl[2][TCH][72];

    int nr0 = r0 + nbase + lr;       // expert-local row (lane's n-col), second set +32
    const int4* wp0 = (const int4*)blocks + (size_t)(e * R1 + nr0) * 128 + kh;
    const int4* wp1 = wp0 + 32 * 128;
    const int*  sp0 = scales + (size_t)(e * R1 + nr0) * 32;
    const int*  sp1 = sp0 + 32 * 32;
    float b0 = bias[e * R1 + nr0];
    float b1 = bias[e * R1 + nr0 + 32];
    int seg8 = (tid & 7) * 8;

    for (int c0 = 0; c0 < cnt; c0 += TCH) {
        int nt = min(TCH, cnt - c0);
        int ntr = (nt + 31) & ~31;
        int nmw = (nt - tok0 + 31) >> 5;
        nmw = nmw < 0 ? 0 : (nmw > 3 ? 3 : nmw);

        // per-thread token row pointers (fixed across K)
        const ushort* tp[6]; bool act[6]; int trow[6];
        #pragma unroll
        for (int j = 0; j < 6; j++) {
            int tok = (tid + j * 256) >> 3;
            trow[j] = tok;
            act[j] = tok < ntr;
            int tok_c = tok < nt ? tok : nt - 1;
            int n = tok_list[e * NTOK + c0 + tok_c];
            tp[j] = t_bf16 + (size_t)n * HD + seg8;
        }

        // prologue: weights kt=0 -> regs; tokens kt=0 -> LDS buf0
        int4 wb[2][4]; int2 sc[2];
        sc[0] = *(const int2*)(sp0);
        sc[1] = *(const int2*)(sp1);
        #pragma unroll
        for (int ks = 0; ks < 4; ks++) {
            int off = (ks >> 1) * 4 + (ks & 1) * 2;
            wb[0][ks] = wp0[off];
            wb[1][ks] = wp1[off];
        }
        #pragma unroll
        for (int j = 0; j < 6; j++) if (act[j]) {
            uint4 tv = *(const uint4*)(tp[j]);
            *(uint4*)&tl[0][trow[j]][seg8] = tv;
        }
        block_fence();

        f32x16 acc[2][3] = {};
        int cur = 0;

        #pragma unroll 1
        for (int kt = 0; kt < 16; kt++) {
            // decode current weights
            bf16x8 wf[2][4];
            #pragma unroll
            for (int rr = 0; rr < 2; rr++) {
                int sA = (rr ? sc[1].x : sc[0].x), sB = (rr ? sc[1].y : sc[0].y);
                unsigned dA16 = (unsigned)((sA - 127) << 7) & 0xFFFFu;
                unsigned dB16 = (unsigned)((sB - 127) << 7) & 0xFFFFu;
                unsigned dA = dA16 | (dA16 << 16), dB = dB16 | (dB16 << 16);
                wf[rr][0] = dec8(wb[rr][0], dA);
                wf[rr][1] = dec8(wb[rr][1], dA);
                wf[rr][2] = dec8(wb[rr][2], dB);
                wf[rr][3] = dec8(wb[rr][3], dB);
            }
            // issue next-step loads: tokens FIRST (so their wait leaves weights in flight)
            uint4 tr[6];
            if (kt < 15) {
                int k1 = (kt + 1) * 64;
                #pragma unroll
                for (int j = 0; j < 6; j++) if (act[j]) tr[j] = *(const uint4*)(tp[j] + k1);
                int g0 = (kt + 1) * 2;
                sc[0] = *(const int2*)(sp0 + g0);
                sc[1] = *(const int2*)(sp1 + g0);
                #pragma unroll
                for (int ks = 0; ks < 4; ks++) {
                    int off = g0 * 4 + (ks >> 1) * 4 + (ks & 1) * 2;
                    wb[0][ks] = wp0[off];
                    wb[1][ks] = wp1[off];
                }
            }
            // MFMA over current token buffer
            #pragma unroll
            for (int ks = 0; ks < 4; ks++) {
                #pragma unroll
                for (int mt = 0; mt < 3; mt++) {
                    if (mt < nmw) {
                        bf16x8 af = *(const bf16x8*)&tl[cur][tok0 + mt * 32 + lr][ks * 16 + kh * 8];
                        acc[0][mt] = __builtin_amdgcn_mfma_f32_32x32x16_bf16(af, wf[0][ks], acc[0][mt], 0, 0, 0);
                        acc[1][mt] = __builtin_amdgcn_mfma_f32_32x32x16_bf16(af, wf[1][ks], acc[1][mt], 0, 0, 0);
                    }
                }
            }
            // write next tokens to other buffer
            if (kt < 15) {
                #pragma unroll
                for (int j = 0; j < 6; j++) if (act[j])
                    *(uint4*)&tl[cur ^ 1][trow[j]][seg8] = tr[j];
            }
            block_fence();
            cur ^= 1;
        }

        // epilogue: bias + swiglu (glu/lin = adjacent lanes), write a[slot][i]
        #pragma unroll
        for (int nn = 0; nn < 2; nn++) {
            float bl = nn ? b1 : b0;
            int col = r0 + nbase + nn * 32 + lr;
            int pcol = col >> 1;
            #pragma unroll
            for (int mt = 0; mt < 3; mt++) {
                #pragma unroll
                for (int r = 0; r < 16; r++) {
                    float h = acc[nn][mt][r] + bl;
                    float other = __shfl_xor(h, 1, 64);
                    int m = (r & 3) + 8 * (r >> 2) + 4 * kh;
                    int tokg = c0 + tok0 + mt * 32 + m;
                    if (!(l & 1) && tokg < cnt) {
                        float hg = fminf(h, 7.0f);
                        float hx = fminf(fmaxf(other, -7.0f), 7.0f);
                        float sig = 1.0f / (1.0f + __expf(-1.702f * hg));
                        float av = hg * sig * (hx + 1.0f);
                        a[(size_t)(base + tokg) * ID + pcol] = (ushort)f2bf(av);
                    }
                }
            }
        }
    }
}

// MLP2 (MFMA). Block: expert x 128 H-rows; same pipeline; writes yb[slot][h].
__global__ __launch_bounds__(256) void k_mlp2(
    const ushort* __restrict__ a, const int* __restrict__ blocks,
    const int* __restrict__ scales, const float* __restrict__ bias,
    const int* __restrict__ counts, const int* __restrict__ offsets,
    ushort* __restrict__ yb)
{
    int e = blockIdx.y;
    int cnt = counts[e];
    if (cnt == 0) return;
    int r0 = blockIdx.x * 128;
    int tid = threadIdx.x;
    int w = tid >> 6, l = tid & 63;
    int lr = l & 31, kh = l >> 5;
    int nbase = (w & 1) * 64;
    int tok0 = (w >> 1) * 96;
    int base = offsets[e];

    __shared__ ushort tl[2][TCH][72];

    int nr0 = r0 + nbase + lr;
    const int4* wp0 = (const int4*)blocks + (size_t)(e * HD + nr0) * 128 + kh;
    const int4* wp1 = wp0 + 32 * 128;
    const int*  sp0 = scales + (size_t)(e * HD + nr0) * 32;
    const int*  sp1 = sp0 + 32 * 32;
    float b0 = bias[e * HD + nr0];
    float b1 = bias[e * HD + nr0 + 32];
    int seg8 = (tid & 7) * 8;

    for (int c0 = 0; c0 < cnt; c0 += TCH) {
        int nt = min(TCH, cnt - c0);
        int ntr = (nt + 31) & ~31;
        int nmw = (nt - tok0 + 31) >> 5;
        nmw = nmw < 0 ? 0 : (nmw > 3 ? 3 : nmw);

        const ushort* tp[6]; bool act[6]; int trow[6];
        #pragma unroll
        for (int j = 0; j < 6; j++) {
            int tok = (tid + j * 256) >> 3;
            trow[j] = tok;
            act[j] = tok < ntr;
            int tok_c = tok < nt ? tok : nt - 1;
            tp[j] = a + (size_t)(base + c0 + tok_c) * ID + seg8;
        }

        int4 wb[2][4]; int2 sc[2];
        sc[0] = *(const int2*)(sp0);
        sc[1] = *(const int2*)(sp1);
        #pragma unroll
        for (int ks = 0; ks < 4; ks++) {
            int off = (ks >> 1) * 4 + (ks & 1) * 2;
            wb[0][ks] = wp0[off];
            wb[1][ks] = wp1[off];
        }
        #pragma unroll
        for (int j = 0; j < 6; j++) if (act[j]) {
            uint4 tv = *(const uint4*)(tp[j]);
            *(uint4*)&tl[0][trow[j]][seg8] = tv;
        }
        block_fence();

        f32x16 acc[2][3] = {};
        int cur = 0;

        #pragma unroll 1
        for (int kt = 0; kt < 16; kt++) {
            bf16x8 wf[2][4];
            #pragma unroll
            for (int rr = 0; rr < 2; rr++) {
                int sA = (rr ? sc[1].x : sc[0].x), sB = (rr ? sc[1].y : sc[0].y);
                unsigned dA16 = (unsigned)((sA - 127) << 7) & 0xFFFFu;
                unsigned dB16 = (unsigned)((sB - 127) << 7) & 0xFFFFu;
                unsigned dA = dA16 | (dA16 << 16), dB = dB16 | (dB16 << 16);
                wf[rr][0] = dec8(wb[rr][0], dA);
                wf[rr][1] = dec8(wb[rr][1], dA);
                wf[rr][2] = dec8(wb[rr][2], dB);
                wf[rr][3] = dec8(wb[rr][3], dB);
            }
            uint4 tr[6];
            if (kt < 15) {
                int k1 = (kt + 1) * 64;
                #pragma unroll
                for (int j = 0; j < 6; j++) if (act[j]) tr[j] = *(const uint4*)(tp[j] + k1);
                int g0 = (kt + 1) * 2;
                sc[0] = *(const int2*)(sp0 + g0);
                sc[1] = *(const int2*)(sp1 + g0);
                #pragma unroll
                for (int ks = 0; ks < 4; ks++) {
                    int off = g0 * 4 + (ks >> 1) * 4 + (ks & 1) * 2;
                    wb[0][ks] = wp0[off];
                    wb[1][ks] = wp1[off];
                }
            }
            #pragma unroll
            for (int ks = 0; ks < 4; ks++) {
                #pragma unroll
                for (int mt = 0; mt < 3; mt++) {
                    if (mt < nmw) {
                        bf16x8 af = *(const bf16x8*)&tl[cur][tok0 + mt * 32 + lr][ks * 16 + kh * 8];
                        acc[0][mt] = __builtin_amdgcn_mfma_f32_32x32x16_bf16(af, wf[0][ks], acc[0][mt], 0, 0, 0);
                        acc[1][mt] = __builtin_amdgcn_mfma_f32_32x32x16_bf16(af, wf[1][ks], acc[1][mt], 0, 0, 0);
                    }
                }
            }
            if (kt < 15) {
                #pragma unroll
                for (int j = 0; j < 6; j++) if (act[j])
                    *(uint4*)&tl[cur ^ 1][trow[j]][seg8] = tr[j];
            }
            block_fence();
            cur ^= 1;
        }

        #pragma unroll
        for (int nn = 0; nn < 2; nn++) {
            float bl = nn ? b1 : b0;
            int col = r0 + nbase + nn * 32 + lr;
            #pragma unroll
            for (int mt = 0; mt < 3; mt++) {
                #pragma unroll
                for (int r = 0; r < 16; r++) {
                    int m = (r & 3) + 8 * (r >> 2) + 4 * kh;
                    int tokg = c0 + tok0 + mt * 32 + m;
                    if (tokg < cnt) {
                        float y = acc[nn][mt][r] + bl;
                        yb[(size_t)(base + tokg) * HD + col] = (ushort)f2bf(y);
                    }
                }
            }
        }
    }
}

__global__ __launch_bounds__(256) void k_combine(
    const float* __restrict__ x, const ushort* __restrict__ yb,
    const int* __restrict__ top_idx, const float* __restrict__ top_wt,
    const int* __restrict__ pos_of, const int* __restrict__ offsets,
    float* __restrict__ out)
{
    int n = blockIdx.x, tid = threadIdx.x;
    float4 xv = ((const float4*)(x + (size_t)n * HD))[tid];
    float r0 = xv.x, r1 = xv.y, r2 = xv.z, r3 = xv.w;
    #pragma unroll
    for (int k = 0; k < 4; k++) {
        int e = top_idx[n * 4 + k];
        float wt = top_wt[n * 4 + k];
        int slot = offsets[e] + pos_of[n * 4 + k];
        ushort4 yv = ((const ushort4*)(yb + (size_t)slot * HD))[tid];
        r0 += wt * bf2f(yv.x); r1 += wt * bf2f(yv.y);
        r2 += wt * bf2f(yv.z); r3 += wt * bf2f(yv.w);
    }
    float4 ov; ov.x = r0; ov.y = r1; ov.z = r2; ov.w = r3;
    ((float4*)(out + (size_t)n * HD))[tid] = ov;
}

extern "C" void kernel_launch(void* const* d_in, const int* in_sizes, int n_in,
                              void* d_out, int out_size, void* d_ws, size_t ws_size,
                              hipStream_t stream)
{
    const float* x           = (const float*)d_in[0];
    const float* norm_w      = (const float*)d_in[1];
    const float* gate_w      = (const float*)d_in[2];
    const float* gate_b      = (const float*)d_in[3];
    const float* mlp1_bias   = (const float*)d_in[4];
    const float* mlp2_bias   = (const float*)d_in[5];
    const int*   mlp1_blocks = (const int*)d_in[6];
    const int*   mlp1_scales = (const int*)d_in[7];
    const int*   mlp2_blocks = (const int*)d_in[8];
    const int*   mlp2_scales = (const int*)d_in[9];
    float* out = (float*)d_out;

    char* ws = (char*)d_ws;
    ushort* t_bf16  = (ushort*)(ws + TB_OFF);
    ushort* a       = (ushort*)(ws + A_OFF);
    ushort* yb      = (ushort*)(ws + YB_OFF);
    int*   counts   = (int*)(ws + CNT_OFF);
    int*   offsets  = (int*)(ws + OFFS_OFF);
    int*   tok_list = (int*)(ws + TOKL_OFF);
    int*   top_idx  = (int*)(ws + TIDX_OFF);
    float* top_wt   = (float*)(ws + TWT_OFF);
    int*   pos_of   = (int*)(ws + POS_OFF);

    hipMemsetAsync(counts, 0, NE * sizeof(int), stream);
    k_gate<<<NTOK, 256, 0, stream>>>(x, norm_w, gate_w, gate_b, t_bf16, top_idx, top_wt,
                                     counts, tok_list, pos_of);
    k_prefix<<<1, 64, 0, stream>>>(counts, offsets);
    k_mlp1<<<dim3(16, NE), 256, 0, stream>>>(t_bf16, mlp1_blocks, mlp1_scales, mlp1_bias,
                                             counts, offsets, tok_list, a);
    k_mlp2<<<dim3(8, NE), 256, 0, stream>>>(a, mlp2_blocks, mlp2_scales, mlp2_bias,
                                            counts, offsets, yb);
    k_combine<<<NTOK, 256, 0, stream>>>(x, yb, top_idx, top_wt, pos_of, offsets, out);
}

// Round 4
// 191.544 us; speedup vs baseline: 1.3017x; 1.3017x over previous
//
#include <hip/hip_runtime.h>
#include <hip/hip_bf16.h>
#include <math.h>

// GPT-OSS MoE: rmsnorm -> gate top4 -> mxfp4 MLP1 (MFMA) -> swiglu -> mxfp4 MLP2 (MFMA) -> combine
// E=32, H=1024, I=1024, N=1024 tokens, top-4.

#define NE 32
#define HD 1024
#define ID 1024
#define NTOK 1024
#define R1 2048

typedef __attribute__((ext_vector_type(8)))  short bf16x8;
typedef __attribute__((ext_vector_type(16))) float f32x16;

// ---- workspace layout (bytes) ----
#define TB_OFF   0            // t_bf16 [1024][1024] bf16 = 2 MB
#define A_OFF    2097152      // a      [4096][1024] bf16 = 8 MB
#define YB_OFF   10485760     // yb     [4096][1024] bf16 = 8 MB
#define CNT_OFF  18874368     // counts int[32]
#define OFFS_OFF 18874624     // offsets int[33]
#define TOKL_OFF 18874880     // tok_list int[32*1024]
#define TIDX_OFF 19005952     // top_idx int[1024*4]
#define TWT_OFF  19022336     // top_wt  f32[1024*4]
#define POS_OFF  19038720     // pos_of  int[1024*4]

__device__ __forceinline__ unsigned f2bf(float f) {
    unsigned u = __float_as_uint(f);
    return (u + 0x7FFFu + ((u >> 16) & 1u)) >> 16;   // RNE
}
__device__ __forceinline__ float bf2f(unsigned u) {
    return __uint_as_float(u << 16);
}

// decode 8 fp4 elems (4 boxed int32s = 4 payload bytes = 8 nibbles) -> bf16x8,
// scale folded in as packed exponent add. fp4 zero -> ~2^-96 after scale (negligible).
__device__ __forceinline__ bf16x8 dec8(int4 wv, unsigned dd) {
    unsigned u = __builtin_amdgcn_perm((unsigned)wv.y, (unsigned)wv.x, 0x00000400u);
    unsigned v = __builtin_amdgcn_perm((unsigned)wv.w, (unsigned)wv.z, 0x04000000u);
    unsigned packed = __builtin_amdgcn_perm(v, u, 0x07060100u);   // {b0,b1,b2,b3}
    unsigned selE = packed & 0x07070707u;
    unsigned sE   = packed & 0x08080808u;
    unsigned ph   = packed >> 4;
    unsigned selO = ph & 0x07070707u;
    unsigned sO   = ph & 0x08080808u;
    const unsigned PH_hi = 0x40404040u, PH_lo = 0x3F3F3F14u;
    const unsigned PL_hi = 0xC0804000u, PL_lo = 0xC0800000u;
    unsigned hbE = __builtin_amdgcn_perm(PH_hi, PH_lo, selE) | (sE << 4);
    unsigned lbE = __builtin_amdgcn_perm(PL_hi, PL_lo, selE);
    unsigned hbO = __builtin_amdgcn_perm(PH_hi, PH_lo, selO) | (sO << 4);
    unsigned lbO = __builtin_amdgcn_perm(PL_hi, PL_lo, selO);
    unsigned mE0 = __builtin_amdgcn_perm(hbE, lbE, 0x05010400u);
    unsigned mE1 = __builtin_amdgcn_perm(hbE, lbE, 0x07030602u);
    unsigned mO0 = __builtin_amdgcn_perm(hbO, lbO, 0x05010400u);
    unsigned mO1 = __builtin_amdgcn_perm(hbO, lbO, 0x07030602u);
    unsigned r0 = __builtin_amdgcn_perm(mO0, mE0, 0x05040100u);
    unsigned r1 = __builtin_amdgcn_perm(mO0, mE0, 0x07060302u);
    unsigned r2 = __builtin_amdgcn_perm(mO1, mE1, 0x05040100u);
    unsigned r3 = __builtin_amdgcn_perm(mO1, mE1, 0x07060302u);
    unsigned o0, o1, o2, o3;
    asm("v_pk_add_u16 %0, %1, %2" : "=v"(o0) : "v"(r0), "v"(dd));
    asm("v_pk_add_u16 %0, %1, %2" : "=v"(o1) : "v"(r1), "v"(dd));
    asm("v_pk_add_u16 %0, %1, %2" : "=v"(o2) : "v"(r2), "v"(dd));
    asm("v_pk_add_u16 %0, %1, %2" : "=v"(o3) : "v"(r3), "v"(dd));
    uint4 o; o.x = o0; o.y = o1; o.z = o2; o.w = o3;
    union { uint4 u4; bf16x8 b; } cv; cv.u4 = o;
    return cv.b;
}

__device__ __forceinline__ void fence_lds() {
    asm volatile("s_waitcnt lgkmcnt(0)" ::: "memory");
    __builtin_amdgcn_sched_barrier(0);
    __builtin_amdgcn_s_barrier();
    __builtin_amdgcn_sched_barrier(0);
}

__global__ __launch_bounds__(256) void k_gate(
    const float* __restrict__ x, const float* __restrict__ norm_w,
    const float* __restrict__ gate_w, const float* __restrict__ gate_b,
    ushort* __restrict__ t_bf16, int* __restrict__ top_idx, float* __restrict__ top_wt,
    int* __restrict__ counts, int* __restrict__ tok_list, int* __restrict__ pos_of)
{
    int n = blockIdx.x;
    int tid = threadIdx.x;
    __shared__ float tl[HD];
    __shared__ float red[4];
    __shared__ float logits[NE];

    const float4* xv = (const float4*)(x + (size_t)n * HD);
    float4 v = xv[tid];
    float ss = v.x * v.x + v.y * v.y + v.z * v.z + v.w * v.w;
    #pragma unroll
    for (int off = 32; off; off >>= 1) ss += __shfl_down(ss, off);
    if ((tid & 63) == 0) red[tid >> 6] = ss;
    __syncthreads();
    float tot = red[0] + red[1] + red[2] + red[3];
    float rms = rsqrtf(tot * (1.0f / HD) + 1e-5f);

    float4 w = ((const float4*)norm_w)[tid];
    float4 tv;
    tv.x = v.x * rms * w.x; tv.y = v.y * rms * w.y;
    tv.z = v.z * rms * w.z; tv.w = v.w * rms * w.w;
    ushort4 tb;
    tb.x = (ushort)f2bf(tv.x); tb.y = (ushort)f2bf(tv.y);
    tb.z = (ushort)f2bf(tv.z); tb.w = (ushort)f2bf(tv.w);
    ((ushort4*)(t_bf16 + (size_t)n * HD))[tid] = tb;
    ((float4*)tl)[tid] = tv;
    __syncthreads();

    int wv = tid >> 6, lane = tid & 63;
    for (int j = 0; j < 8; j++) {
        int e = wv * 8 + j;
        const float* gw = gate_w + (size_t)e * HD;
        float p = 0.f;
        #pragma unroll
        for (int q = 0; q < 16; q++) { int kk = lane + q * 64; p += tl[kk] * gw[kk]; }
        #pragma unroll
        for (int off = 32; off; off >>= 1) p += __shfl_down(p, off);
        if (lane == 0) logits[e] = p + gate_b[e];
    }
    __syncthreads();

    if (tid == 0) {
        float vals[4]; int idx[4];
        unsigned used = 0;
        #pragma unroll
        for (int kk = 0; kk < 4; kk++) {
            float best = -1e30f; int bi = 0;
            for (int e2 = 0; e2 < NE; e2++) {
                if (used & (1u << e2)) continue;
                if (logits[e2] > best) { best = logits[e2]; bi = e2; }
            }
            used |= 1u << bi; vals[kk] = best; idx[kk] = bi;
        }
        float m = vals[0], s = 0.f, ex[4];
        #pragma unroll
        for (int kk = 0; kk < 4; kk++) { ex[kk] = __expf(vals[kk] - m); s += ex[kk]; }
        float inv = 1.0f / s;
        #pragma unroll
        for (int kk = 0; kk < 4; kk++) {
            top_idx[n * 4 + kk] = idx[kk];
            top_wt[n * 4 + kk] = ex[kk] * inv;
            int slot = atomicAdd(counts + idx[kk], 1);
            tok_list[idx[kk] * NTOK + slot] = n;
            pos_of[n * 4 + kk] = slot;
        }
    }
}

__global__ void k_prefix(const int* __restrict__ counts, int* __restrict__ offsets)
{
    if (threadIdx.x == 0) {
        int s = 0;
        for (int e = 0; e < NE; e++) { offsets[e] = s; s += counts[e]; }
        offsets[NE] = s;
    }
}

// MLP1 (MFMA) + swiglu. Block: expert x 128 rows x 64-token chunk (blockIdx.z).
// 4 waves x 32 rows, all share the token tile. Weights: global->reg (depth-2 prefetch)
// ->dec8->MFMA, never LDS. Tokens: LDS double-buffered, depth-2 reg prefetch.
__global__ __launch_bounds__(256) void k_mlp1(
    const ushort* __restrict__ t_bf16, const int* __restrict__ blocks,
    const int* __restrict__ scales, const float* __restrict__ bias,
    const int* __restrict__ counts, const int* __restrict__ offsets,
    const int* __restrict__ tok_list, ushort* __restrict__ a)
{
    int e = blockIdx.y;
    int cnt = counts[e];
    int r0 = blockIdx.x * 128;
    int tid = threadIdx.x;
    int l = tid & 63;
    int lr = l & 31, kh = l >> 5;
    int base = offsets[e];

    __shared__ ushort tl[2][64][72];   // 18 KB, stride 144B = 9 x 16B (conflict-free b128)

    int row = r0 + (tid >> 6) * 32 + lr;
    const int4* wp = (const int4*)blocks + (size_t)(e * R1 + row) * 128 + kh;
    const int*  sp = scales + (size_t)(e * R1 + row) * 32;
    float bl = bias[e * R1 + row];
    int srow = tid & 63;
    int scol0 = (tid >> 6) * 8;
    int scol1 = scol0 + 32;

    for (int c0 = blockIdx.z * 64; c0 < cnt; c0 += 256) {
        int nt = min(64, cnt - c0);
        int nmt = (nt + 31) >> 5;
        const ushort* tp = t_bf16 + (size_t)tok_list[e * NTOK + c0 + min(srow, nt - 1)] * HD;

        // prologue: tokens kt=0 first (ds_write's wait leaves weight loads in flight)
        uint4 t0a = *(const uint4*)(tp + scol0);
        uint4 t0b = *(const uint4*)(tp + scol1);
        int4 wbA[4], wbB[4]; int2 scA, scB;
        #pragma unroll
        for (int ks = 0; ks < 4; ks++) wbA[ks] = wp[2 * ks];
        scA = *(const int2*)sp;
        #pragma unroll
        for (int ks = 0; ks < 4; ks++) wbB[ks] = wp[8 + 2 * ks];
        scB = *(const int2*)(sp + 2);
        uint4 tra = *(const uint4*)(tp + 64 + scol0);
        uint4 trb = *(const uint4*)(tp + 64 + scol1);
        *(uint4*)&tl[0][srow][scol0] = t0a;
        *(uint4*)&tl[0][srow][scol1] = t0b;
        fence_lds();

        f32x16 acc[2] = {};

        #pragma unroll 1
        for (int kt2 = 0; kt2 < 16; kt2 += 2) {
            #pragma unroll
            for (int h = 0; h < 2; h++) {
                int kt = kt2 + h;
                int sA = h ? scB.x : scA.x;
                int sB = h ? scB.y : scA.y;
                unsigned dA16 = (unsigned)((sA - 127) << 7) & 0xFFFFu;
                unsigned dB16 = (unsigned)((sB - 127) << 7) & 0xFFFFu;
                unsigned dA = dA16 | (dA16 << 16), dB = dB16 | (dB16 << 16);
                bf16x8 wf0 = dec8(h ? wbB[0] : wbA[0], dA);
                bf16x8 wf1 = dec8(h ? wbB[1] : wbA[1], dA);
                bf16x8 wf2 = dec8(h ? wbB[2] : wbA[2], dB);
                bf16x8 wf3 = dec8(h ? wbB[3] : wbA[3], dB);
                if (kt < 15) {                        // ds_write T(kt+1)
                    *(uint4*)&tl[h ^ 1][srow][scol0] = tra;
                    *(uint4*)&tl[h ^ 1][srow][scol1] = trb;
                }
                if (kt < 14) {                        // issue T(kt+2), W(kt+2)
                    const ushort* tpk = tp + (kt + 2) * 64;
                    tra = *(const uint4*)(tpk + scol0);
                    trb = *(const uint4*)(tpk + scol1);
                    int woff = (kt + 2) * 8;
                    if (h) {
                        #pragma unroll
                        for (int ks = 0; ks < 4; ks++) wbB[ks] = wp[woff + 2 * ks];
                        scB = *(const int2*)(sp + (kt + 2) * 2);
                    } else {
                        #pragma unroll
                        for (int ks = 0; ks < 4; ks++) wbA[ks] = wp[woff + 2 * ks];
                        scA = *(const int2*)(sp + (kt + 2) * 2);
                    }
                }
                #pragma unroll
                for (int mt = 0; mt < 2; mt++) {
                    if (mt < nmt) {
                        bf16x8 af0 = *(const bf16x8*)&tl[h][mt * 32 + lr][kh * 8];
                        acc[mt] = __builtin_amdgcn_mfma_f32_32x32x16_bf16(af0, wf0, acc[mt], 0, 0, 0);
                        bf16x8 af1 = *(const bf16x8*)&tl[h][mt * 32 + lr][16 + kh * 8];
                        acc[mt] = __builtin_amdgcn_mfma_f32_32x32x16_bf16(af1, wf1, acc[mt], 0, 0, 0);
                        bf16x8 af2 = *(const bf16x8*)&tl[h][mt * 32 + lr][32 + kh * 8];
                        acc[mt] = __builtin_amdgcn_mfma_f32_32x32x16_bf16(af2, wf2, acc[mt], 0, 0, 0);
                        bf16x8 af3 = *(const bf16x8*)&tl[h][mt * 32 + lr][48 + kh * 8];
                        acc[mt] = __builtin_amdgcn_mfma_f32_32x32x16_bf16(af3, wf3, acc[mt], 0, 0, 0);
                    }
                }
                fence_lds();
            }
        }

        // epilogue: bias + swiglu (glu/lin = adjacent lanes = adjacent rows)
        #pragma unroll
        for (int mt = 0; mt < 2; mt++) {
            #pragma unroll
            for (int r = 0; r < 16; r++) {
                float hv = acc[mt][r] + bl;
                float other = __shfl_xor(hv, 1, 64);
                int m = (r & 3) + 8 * (r >> 2) + 4 * kh;
                int tokg = c0 + mt * 32 + m;
                if (!(l & 1) && tokg < cnt) {
                    float hg = fminf(hv, 7.0f);
                    float hx = fminf(fmaxf(other, -7.0f), 7.0f);
                    float sig = 1.0f / (1.0f + __expf(-1.702f * hg));
                    float av = hg * sig * (hx + 1.0f);
                    a[(size_t)(base + tokg) * ID + (row >> 1)] = (ushort)f2bf(av);
                }
            }
        }
    }
}

// MLP2 (MFMA). Block: expert x 128 H-rows x 64-token chunk. Writes yb[slot][h].
__global__ __launch_bounds__(256) void k_mlp2(
    const ushort* __restrict__ a, const int* __restrict__ blocks,
    const int* __restrict__ scales, const float* __restrict__ bias,
    const int* __restrict__ counts, const int* __restrict__ offsets,
    ushort* __restrict__ yb)
{
    int e = blockIdx.y;
    int cnt = counts[e];
    int r0 = blockIdx.x * 128;
    int tid = threadIdx.x;
    int l = tid & 63;
    int lr = l & 31, kh = l >> 5;
    int base = offsets[e];

    __shared__ ushort tl[2][64][72];

    int row = r0 + (tid >> 6) * 32 + lr;
    const int4* wp = (const int4*)blocks + (size_t)(e * HD + row) * 128 + kh;
    const int*  sp = scales + (size_t)(e * HD + row) * 32;
    float bl = bias[e * HD + row];
    int srow = tid & 63;
    int scol0 = (tid >> 6) * 8;
    int scol1 = scol0 + 32;

    for (int c0 = blockIdx.z * 64; c0 < cnt; c0 += 256) {
        int nt = min(64, cnt - c0);
        int nmt = (nt + 31) >> 5;
        const ushort* tp = a + (size_t)(base + c0 + min(srow, nt - 1)) * ID;

        uint4 t0a = *(const uint4*)(tp + scol0);
        uint4 t0b = *(const uint4*)(tp + scol1);
        int4 wbA[4], wbB[4]; int2 scA, scB;
        #pragma unroll
        for (int ks = 0; ks < 4; ks++) wbA[ks] = wp[2 * ks];
        scA = *(const int2*)sp;
        #pragma unroll
        for (int ks = 0; ks < 4; ks++) wbB[ks] = wp[8 + 2 * ks];
        scB = *(const int2*)(sp + 2);
        uint4 tra = *(const uint4*)(tp + 64 + scol0);
        uint4 trb = *(const uint4*)(tp + 64 + scol1);
        *(uint4*)&tl[0][srow][scol0] = t0a;
        *(uint4*)&tl[0][srow][scol1] = t0b;
        fence_lds();

        f32x16 acc[2] = {};

        #pragma unroll 1
        for (int kt2 = 0; kt2 < 16; kt2 += 2) {
            #pragma unroll
            for (int h = 0; h < 2; h++) {
                int kt = kt2 + h;
                int sA = h ? scB.x : scA.x;
                int sB = h ? scB.y : scA.y;
                unsigned dA16 = (unsigned)((sA - 127) << 7) & 0xFFFFu;
                unsigned dB16 = (unsigned)((sB - 127) << 7) & 0xFFFFu;
                unsigned dA = dA16 | (dA16 << 16), dB = dB16 | (dB16 << 16);
                bf16x8 wf0 = dec8(h ? wbB[0] : wbA[0], dA);
                bf16x8 wf1 = dec8(h ? wbB[1] : wbA[1], dA);
                bf16x8 wf2 = dec8(h ? wbB[2] : wbA[2], dB);
                bf16x8 wf3 = dec8(h ? wbB[3] : wbA[3], dB);
                if (kt < 15) {
                    *(uint4*)&tl[h ^ 1][srow][scol0] = tra;
                    *(uint4*)&tl[h ^ 1][srow][scol1] = trb;
                }
                if (kt < 14) {
                    const ushort* tpk = tp + (kt + 2) * 64;
                    tra = *(const uint4*)(tpk + scol0);
                    trb = *(const uint4*)(tpk + scol1);
                    int woff = (kt + 2) * 8;
                    if (h) {
                        #pragma unroll
                        for (int ks = 0; ks < 4; ks++) wbB[ks] = wp[woff + 2 * ks];
                        scB = *(const int2*)(sp + (kt + 2) * 2);
                    } else {
                        #pragma unroll
                        for (int ks = 0; ks < 4; ks++) wbA[ks] = wp[woff + 2 * ks];
                        scA = *(const int2*)(sp + (kt + 2) * 2);
                    }
                }
                #pragma unroll
                for (int mt = 0; mt < 2; mt++) {
                    if (mt < nmt) {
                        bf16x8 af0 = *(const bf16x8*)&tl[h][mt * 32 + lr][kh * 8];
                        acc[mt] = __builtin_amdgcn_mfma_f32_32x32x16_bf16(af0, wf0, acc[mt], 0, 0, 0);
                        bf16x8 af1 = *(const bf16x8*)&tl[h][mt * 32 + lr][16 + kh * 8];
                        acc[mt] = __builtin_amdgcn_mfma_f32_32x32x16_bf16(af1, wf1, acc[mt], 0, 0, 0);
                        bf16x8 af2 = *(const bf16x8*)&tl[h][mt * 32 + lr][32 + kh * 8];
                        acc[mt] = __builtin_amdgcn_mfma_f32_32x32x16_bf16(af2, wf2, acc[mt], 0, 0, 0);
                        bf16x8 af3 = *(const bf16x8*)&tl[h][mt * 32 + lr][48 + kh * 8];
                        acc[mt] = __builtin_amdgcn_mfma_f32_32x32x16_bf16(af3, wf3, acc[mt], 0, 0, 0);
                    }
                }
                fence_lds();
            }
        }

        #pragma unroll
        for (int mt = 0; mt < 2; mt++) {
            #pragma unroll
            for (int r = 0; r < 16; r++) {
                int m = (r & 3) + 8 * (r >> 2) + 4 * kh;
                int tokg = c0 + mt * 32 + m;
                if (tokg < cnt) {
                    float y = acc[mt][r] + bl;
                    yb[(size_t)(base + tokg) * HD + row] = (ushort)f2bf(y);
                }
            }
        }
    }
}

__global__ __launch_bounds__(256) void k_combine(
    const float* __restrict__ x, const ushort* __restrict__ yb,
    const int* __restrict__ top_idx, const float* __restrict__ top_wt,
    const int* __restrict__ pos_of, const int* __restrict__ offsets,
    float* __restrict__ out)
{
    int n = blockIdx.x, tid = threadIdx.x;
    float4 xv = ((const float4*)(x + (size_t)n * HD))[tid];
    float r0 = xv.x, r1 = xv.y, r2 = xv.z, r3 = xv.w;
    #pragma unroll
    for (int k = 0; k < 4; k++) {
        int e = top_idx[n * 4 + k];
        float wt = top_wt[n * 4 + k];
        int slot = offsets[e] + pos_of[n * 4 + k];
        ushort4 yv = ((const ushort4*)(yb + (size_t)slot * HD))[tid];
        r0 += wt * bf2f(yv.x); r1 += wt * bf2f(yv.y);
        r2 += wt * bf2f(yv.z); r3 += wt * bf2f(yv.w);
    }
    float4 ov; ov.x = r0; ov.y = r1; ov.z = r2; ov.w = r3;
    ((float4*)(out + (size_t)n * HD))[tid] = ov;
}

extern "C" void kernel_launch(void* const* d_in, const int* in_sizes, int n_in,
                              void* d_out, int out_size, void* d_ws, size_t ws_size,
                              hipStream_t stream)
{
    const float* x           = (const float*)d_in[0];
    const float* norm_w      = (const float*)d_in[1];
    const float* gate_w      = (const float*)d_in[2];
    const float* gate_b      = (const float*)d_in[3];
    const float* mlp1_bias   = (const float*)d_in[4];
    const float* mlp2_bias   = (const float*)d_in[5];
    const int*   mlp1_blocks = (const int*)d_in[6];
    const int*   mlp1_scales = (const int*)d_in[7];
    const int*   mlp2_blocks = (const int*)d_in[8];
    const int*   mlp2_scales = (const int*)d_in[9];
    float* out = (float*)d_out;

    char* ws = (char*)d_ws;
    ushort* t_bf16  = (ushort*)(ws + TB_OFF);
    ushort* a       = (ushort*)(ws + A_OFF);
    ushort* yb      = (ushort*)(ws + YB_OFF);
    int*   counts   = (int*)(ws + CNT_OFF);
    int*   offsets  = (int*)(ws + OFFS_OFF);
    int*   tok_list = (int*)(ws + TOKL_OFF);
    int*   top_idx  = (int*)(ws + TIDX_OFF);
    float* top_wt   = (float*)(ws + TWT_OFF);
    int*   pos_of   = (int*)(ws + POS_OFF);

    hipMemsetAsync(counts, 0, NE * sizeof(int), stream);
    k_gate<<<NTOK, 256, 0, stream>>>(x, norm_w, gate_w, gate_b, t_bf16, top_idx, top_wt,
                                     counts, tok_list, pos_of);
    k_prefix<<<1, 64, 0, stream>>>(counts, offsets);
    k_mlp1<<<dim3(16, NE, 4), 256, 0, stream>>>(t_bf16, mlp1_blocks, mlp1_scales, mlp1_bias,
                                                counts, offsets, tok_list, a);
    k_mlp2<<<dim3(8, NE, 4), 256, 0, stream>>>(a, mlp2_blocks, mlp2_scales, mlp2_bias,
                                               counts, offsets, yb);
    k_combine<<<NTOK, 256, 0, stream>>>(x, yb, top_idx, top_wt, pos_of, offsets, out);
}